// Round 8
// baseline (115.783 us; speedup 1.0000x reference)
//
#include <hip/hip_runtime.h>

typedef _Float16 half8 __attribute__((ext_vector_type(8)));
typedef _Float16 half4_t __attribute__((ext_vector_type(4)));
typedef short short8 __attribute__((ext_vector_type(8)));
typedef unsigned short u16x4 __attribute__((ext_vector_type(4)));
typedef float f32x4 __attribute__((ext_vector_type(4)));

#define NH 8

__device__ __forceinline__ unsigned short f2bf(float x) {
  union { float f; unsigned u; } v; v.f = x;
  unsigned r = v.u + 0x7FFFu + ((v.u >> 16) & 1u);
  return (unsigned short)(r >> 16);
}

#define DRAIN_BAR()                                  \
  asm volatile("s_waitcnt lgkmcnt(0)" ::: "memory"); \
  __builtin_amdgcn_s_barrier();                      \
  __builtin_amdgcn_sched_barrier(0)

// ---------------- K0a: q/k weights -> fragment-major [h][kc][k8][o][8] fp16 ----
__global__ __launch_bounds__(256) void k0_qk(
    const float* __restrict__ wq, const float* __restrict__ wk,
    const float* __restrict__ omega,
    _Float16* __restrict__ wxq, _Float16* __restrict__ wxk) {
  const int bid = blockIdx.x;
  const int arr = bid >> 7;
  const int h = (bid >> 4) & 7;
  const int ft = (bid >> 1) & 7;
  const int os = bid & 1;
  const int f = threadIdx.x & 63;
  const int w = threadIdx.x >> 6;
  const float* wsrc = (arr ? wk : wq) + ((size_t)h * 512 + ft * 64 + f) * 64;
  float wreg[64];
#pragma unroll
  for (int i = 0; i < 16; ++i) {
    float4 v = *(const float4*)(wsrc + i * 4);
    wreg[i * 4] = v.x; wreg[i * 4 + 1] = v.y; wreg[i * 4 + 2] = v.z; wreg[i * 4 + 3] = v.w;
  }
  _Float16* outp = arr ? wxk : wxq;
  const int k8 = f >> 3, e = f & 7;
#pragma unroll 1
  for (int oo = 0; oo < 8; ++oo) {
    const int o = w * 16 + os * 8 + oo;
    const float* om = omega + o * 64;
    float s = 0.f;
#pragma unroll
    for (int k = 0; k < 64; ++k) s = fmaf(wreg[k], om[k], s);
    outp[((((size_t)h * 8 + ft) * 8 + k8) * 64 + o) * 8 + e] = (_Float16)s;
  }
}

// ---------------- K0b: v weights -> fragment-major [h][kc][k8][o][8] fp16 ------
__global__ __launch_bounds__(256) void k0_v(
    const float* __restrict__ wv, _Float16* __restrict__ wvt) {
  int idx = blockIdx.x * 256 + threadIdx.x;  // 262144
  int h = idx >> 15, o = (idx >> 9) & 63, f = idx & 511;
  float val = wv[((size_t)h * 512 + f) * 64 + o];
  wvt[((((size_t)h * 8 + (f >> 6)) * 8 + ((f >> 3) & 7)) * 64 + o) * 8 + (f & 7)] = (_Float16)val;
}

// ---------------- fused_kv: 2 heads/block, dbuf staging, per-head kv-GEMM ------
// grid 256 = hp(4, top) x b(4) x sc(16); block 512 = 8 waves = (head hh, row-quarter rq)
__global__ __launch_bounds__(512, 1) void fused_kv(
    const float* __restrict__ key, const float* __restrict__ value,
    const _Float16* __restrict__ wxk, const _Float16* __restrict__ wvt,
    float* __restrict__ kvpart) {
  __shared__ __align__(16) _Float16 A[2][128][72];       // 36864 B
  __shared__ __align__(16) _Float16 W[2][2][4096];       // 32768 B
  __shared__ __align__(16) unsigned short kpT[128][136]; // 34816 B
  __shared__ __align__(16) unsigned short vT[64][136];   // 17408 B
  const int bid = blockIdx.x;
  const int hp = bid >> 6;
  const int b = (bid >> 4) & 3;
  const int sc = bid & 15;
  const int s0 = sc * 256;
  const int tid = threadIdx.x;
  const int w = tid >> 6;
  const int lane = tid & 63;
  const int g = lane >> 4, c = lane & 15;
  const int hh = w >> 2;       // head within pair
  const int rq = w & 3;        // row quarter
  const int xr = lane >> 4;
  const int xc = (lane & 15) * 4;

  const _Float16* wkb0 = wxk + (size_t)(hp * 2) * 32768;
  const _Float16* wkb1 = wkb0 + 32768;
  const _Float16* wvb0 = wvt + (size_t)(hp * 2) * 32768;
  const _Float16* wvb1 = wvb0 + 32768;

  short8 bones;
#pragma unroll
  for (int i = 0; i < 8; ++i) bones[i] = (c == 0) ? (short)0x3F80 : (short)0;

  f32x4 acc_kv[2][5];
#pragma unroll
  for (int h2 = 0; h2 < 2; ++h2)
#pragma unroll
    for (int j = 0; j < 5; ++j) acc_kv[h2][j] = (f32x4){0.f, 0.f, 0.f, 0.f};

  u16x4 kps[2][4], kms[2][4], vs_[2][4];

  float4 xv[4];
  half8 wr0, wr1;

#pragma unroll 1
  for (int p = 0; p < 4; ++p) {
    const float* xb = ((p & 1) ? value : key) +
                      (size_t)(b * 4096 + s0 + (p >> 1) * 128 + w * 16 + xr) * 512 + xc;
    const _Float16* wb0 = (p & 1) ? wvb0 : wkb0;
    const _Float16* wb1 = (p & 1) ? wvb1 : wkb1;

    // prologue: tile 0 -> buf0; tile 1 -> regs
#pragma unroll
    for (int i = 0; i < 4; ++i) xv[i] = *(const float4*)(xb + i * 2048);
    wr0 = *(const half8*)(wb0 + tid * 8);
    wr1 = *(const half8*)(wb1 + tid * 8);
#pragma unroll
    for (int i = 0; i < 4; ++i) {
      float vv[4] = {xv[i].x, xv[i].y, xv[i].z, xv[i].w};
      half4_t hv;
#pragma unroll
      for (int j2 = 0; j2 < 4; ++j2) hv[j2] = (_Float16)vv[j2];
      *(half4_t*)&A[0][w * 16 + i * 4 + xr][xc] = hv;
    }
    *(half8*)&W[0][0][tid * 8] = wr0;
    *(half8*)&W[0][1][tid * 8] = wr1;
#pragma unroll
    for (int i = 0; i < 4; ++i) xv[i] = *(const float4*)(xb + 64 + i * 2048);
    wr0 = *(const half8*)(wb0 + 4096 + tid * 8);
    wr1 = *(const half8*)(wb1 + 4096 + tid * 8);
    DRAIN_BAR();

    f32x4 accp[2][4];
#pragma unroll
    for (int mf = 0; mf < 2; ++mf)
#pragma unroll
      for (int j = 0; j < 4; ++j) accp[mf][j] = (f32x4){0.f, 0.f, 0.f, 0.f};

#pragma unroll 1
    for (int kc = 0; kc < 8; ++kc) {
      const int cur = kc & 1;
      if (kc < 7) {
        const int nxt = cur ^ 1;
#pragma unroll
        for (int i = 0; i < 4; ++i) {
          float vv[4] = {xv[i].x, xv[i].y, xv[i].z, xv[i].w};
          half4_t hv;
#pragma unroll
          for (int j2 = 0; j2 < 4; ++j2) hv[j2] = (_Float16)vv[j2];
          *(half4_t*)&A[nxt][w * 16 + i * 4 + xr][xc] = hv;
        }
        *(half8*)&W[nxt][0][tid * 8] = wr0;
        *(half8*)&W[nxt][1][tid * 8] = wr1;
        if (kc < 6) {
#pragma unroll
          for (int i = 0; i < 4; ++i)
            xv[i] = *(const float4*)(xb + (kc + 2) * 64 + i * 2048);
          wr0 = *(const half8*)(wb0 + (kc + 2) * 4096 + tid * 8);
          wr1 = *(const half8*)(wb1 + (kc + 2) * 4096 + tid * 8);
        }
      }
#pragma unroll
      for (int ks = 0; ks < 2; ++ks) {
        half8 af0 = *(const half8*)&A[cur][rq * 32 + c][ks * 32 + g * 8];
        half8 af1 = *(const half8*)&A[cur][rq * 32 + 16 + c][ks * 32 + g * 8];
#pragma unroll
        for (int nf = 0; nf < 4; ++nf) {
          half8 wf = *(const half8*)&W[cur][hh][((ks * 4 + g) * 64 + nf * 16 + c) * 8];
          accp[0][nf] = __builtin_amdgcn_mfma_f32_16x16x32_f16(af0, wf, accp[0][nf], 0, 0, 0);
          accp[1][nf] = __builtin_amdgcn_mfma_f32_16x16x32_f16(af1, wf, accp[1][nf], 0, 0, 0);
        }
      }
      DRAIN_BAR();
    }

    if ((p & 1) == 0) {  // key phase: phi -> stash
#pragma unroll
      for (int mf = 0; mf < 2; ++mf) {
        float ss_[4];
#pragma unroll
        for (int j = 0; j < 4; ++j) {
          float s = 0.f;
#pragma unroll
          for (int nf = 0; nf < 4; ++nf) { float q = accp[mf][nf][j]; s = fmaf(q, q, s); }
          s += __shfl_xor(s, 1); s += __shfl_xor(s, 2);
          s += __shfl_xor(s, 4); s += __shfl_xor(s, 8);
          ss_[j] = s * 0.0078125f;  // ||xw||^2/128 == 0.5||k||^2
        }
#pragma unroll
        for (int nf = 0; nf < 4; ++nf) {
          u16x4 kp_p, kp_m;
#pragma unroll
          for (int j = 0; j < 4; ++j) {
            float v = accp[mf][nf][j];
            kp_p[j] = f2bf(__expf(v - ss_[j]) + 1e-9f);
            kp_m[j] = f2bf(__expf(-v - ss_[j]) + 1e-9f);
          }
          kps[mf][nf] = kp_p;
          kms[mf][nf] = kp_m;
        }
      }
    } else {  // value phase: stash v, then per-head kv-GEMM
#pragma unroll
      for (int mf = 0; mf < 2; ++mf)
#pragma unroll
        for (int nf = 0; nf < 4; ++nf) {
          u16x4 vv;
#pragma unroll
          for (int j = 0; j < 4; ++j) vv[j] = f2bf(accp[mf][nf][j]);
          vs_[mf][nf] = vv;
        }
#pragma unroll
      for (int h2 = 0; h2 < 2; ++h2) {
        if (hh == h2) {
#pragma unroll
          for (int mf = 0; mf < 2; ++mf)
#pragma unroll
            for (int nf = 0; nf < 4; ++nf) {
              const int m = nf * 16 + c;
              const int sl = rq * 32 + mf * 16 + g * 4;
              *(u16x4*)&kpT[m][sl] = kps[mf][nf];
              *(u16x4*)&kpT[64 + m][sl] = kms[mf][nf];
              *(u16x4*)&vT[m][sl] = vs_[mf][nf];
            }
        }
        DRAIN_BAR();
#pragma unroll
        for (int ks = 0; ks < 4; ++ks) {
          short8 a = *(const short8*)&kpT[w * 16 + c][ks * 32 + g * 8];
#pragma unroll
          for (int nf = 0; nf < 4; ++nf) {
            short8 bb = *(const short8*)&vT[nf * 16 + c][ks * 32 + g * 8];
            acc_kv[h2][nf] = __builtin_amdgcn_mfma_f32_16x16x32_bf16(a, bb, acc_kv[h2][nf], 0, 0, 0);
          }
          acc_kv[h2][4] = __builtin_amdgcn_mfma_f32_16x16x32_bf16(a, bones, acc_kv[h2][4], 0, 0, 0);
        }
        __builtin_amdgcn_s_barrier();
      }
    }
  }

#pragma unroll
  for (int h2 = 0; h2 < 2; ++h2) {
    float* pbase = kvpart + ((size_t)sc * 32 + b * 8 + hp * 2 + h2) * 10240;
#pragma unroll
    for (int nf = 0; nf < 5; ++nf)
#pragma unroll
      for (int j = 0; j < 4; ++j)
        pbase[(w * 16 + g * 4 + j) * 80 + nf * 16 + c] = acc_kv[h2][nf][j];
  }
}

// ---------------- k3a: denominator sums -> inv + lsc (tiny) ----------------
__global__ __launch_bounds__(128) void k3a_denom(
    const float* __restrict__ kvpart, float* __restrict__ invbuf,
    float* __restrict__ lsc) {
  const int bh = blockIdx.x;
  const int m = threadIdx.x;
  const float* base = kvpart + (size_t)bh * 10240 + m * 80 + 64;
  float s = 0.f;
#pragma unroll
  for (int kk = 0; kk < 16; ++kk) s += base[(size_t)kk * 327680];
  invbuf[bh * 128 + m] = 1.0f / s;
  lsc[bh * 128 + m] = __logf(s);
}

// ---------------- k3b: coalesced elementwise reduce + normalize ----------------
__global__ __launch_bounds__(256) void k3b_reduce(
    const float* __restrict__ kvpart, const float* __restrict__ invbuf,
    _Float16* __restrict__ kvnt) {
  const int bh = blockIdx.x;
  const int e0 = blockIdx.y * 1024 + threadIdx.x * 4;
  const int m = e0 / 80;
  const int d0 = e0 - m * 80;
  const float* base = kvpart + (size_t)bh * 10240 + e0;
  f32x4 s = (f32x4){0.f, 0.f, 0.f, 0.f};
#pragma unroll
  for (int kk = 0; kk < 16; ++kk) {
    f32x4 v = *(const f32x4*)(base + (size_t)kk * 327680);
    s += v;
  }
  const float inv = invbuf[bh * 128 + m];
  const int mst = ((m & 63) << 1) | (m >> 6);
  _Float16* outb = kvnt + (size_t)bh * 10240 + mst;
#pragma unroll
  for (int j = 0; j < 4; ++j) {
    const int d = d0 + j;
    float val;
    if (d < 64) val = s[j] * inv;
    else if (d == 64) val = 1.0f;
    else val = 0.f;
    outb[d * 128] = (_Float16)val;
  }
}

// ---------------- fused_qo: 2 heads/block, dbuf, per-head out-GEMM -------------
// grid 512 = hp(4, top) x rt(128); block 512 = 8 waves = (hh, rq)
__global__ __launch_bounds__(512, 1) void fused_qo(
    const float* __restrict__ query, const _Float16* __restrict__ wxq,
    const _Float16* __restrict__ kvnt, const float* __restrict__ lsc,
    float* __restrict__ out) {
  __shared__ __align__(16) _Float16 A[2][128][72];   // 36864 B
  __shared__ __align__(16) _Float16 W[2][2][4096];   // 32768 B
  __shared__ __align__(16) _Float16 qpT[128][136];   // 34816 B
  const int bid = blockIdx.x;
  const int hp = bid >> 7;
  const int rt = bid & 127;
  const int b = rt >> 5;
  const int t0 = (rt & 31) * 128;
  const int tid = threadIdx.x;
  const int w = tid >> 6;
  const int lane = tid & 63;
  const int g = lane >> 4, c = lane & 15;
  const int hh = w >> 2;
  const int rq = w & 3;
  const int xr = lane >> 4;
  const int xc = (lane & 15) * 4;

  const float* xb = query + (size_t)(rt * 128 + w * 16 + xr) * 512 + xc;
  const _Float16* wb0 = wxq + (size_t)(hp * 2) * 32768;
  const _Float16* wb1 = wb0 + 32768;

  float4 xv[4];
  half8 wr0, wr1;
#pragma unroll
  for (int i = 0; i < 4; ++i) xv[i] = *(const float4*)(xb + i * 2048);
  wr0 = *(const half8*)(wb0 + tid * 8);
  wr1 = *(const half8*)(wb1 + tid * 8);
#pragma unroll
  for (int i = 0; i < 4; ++i) {
    float vv[4] = {xv[i].x, xv[i].y, xv[i].z, xv[i].w};
    half4_t hv;
#pragma unroll
    for (int j2 = 0; j2 < 4; ++j2) hv[j2] = (_Float16)vv[j2];
    *(half4_t*)&A[0][w * 16 + i * 4 + xr][xc] = hv;
  }
  *(half8*)&W[0][0][tid * 8] = wr0;
  *(half8*)&W[0][1][tid * 8] = wr1;
#pragma unroll
  for (int i = 0; i < 4; ++i) xv[i] = *(const float4*)(xb + 64 + i * 2048);
  wr0 = *(const half8*)(wb0 + 4096 + tid * 8);
  wr1 = *(const half8*)(wb1 + 4096 + tid * 8);
  DRAIN_BAR();

  f32x4 accp[2][4];
#pragma unroll
  for (int mf = 0; mf < 2; ++mf)
#pragma unroll
    for (int j = 0; j < 4; ++j) accp[mf][j] = (f32x4){0.f, 0.f, 0.f, 0.f};

#pragma unroll 1
  for (int kc = 0; kc < 8; ++kc) {
    const int cur = kc & 1;
    if (kc < 7) {
      const int nxt = cur ^ 1;
#pragma unroll
      for (int i = 0; i < 4; ++i) {
        float vv[4] = {xv[i].x, xv[i].y, xv[i].z, xv[i].w};
        half4_t hv;
#pragma unroll
        for (int j2 = 0; j2 < 4; ++j2) hv[j2] = (_Float16)vv[j2];
        *(half4_t*)&A[nxt][w * 16 + i * 4 + xr][xc] = hv;
      }
      *(half8*)&W[nxt][0][tid * 8] = wr0;
      *(half8*)&W[nxt][1][tid * 8] = wr1;
      if (kc < 6) {
#pragma unroll
        for (int i = 0; i < 4; ++i)
          xv[i] = *(const float4*)(xb + (kc + 2) * 64 + i * 2048);
        wr0 = *(const half8*)(wb0 + (kc + 2) * 4096 + tid * 8);
        wr1 = *(const half8*)(wb1 + (kc + 2) * 4096 + tid * 8);
      }
    }
#pragma unroll
    for (int ks = 0; ks < 2; ++ks) {
      half8 af0 = *(const half8*)&A[cur][rq * 32 + c][ks * 32 + g * 8];
      half8 af1 = *(const half8*)&A[cur][rq * 32 + 16 + c][ks * 32 + g * 8];
#pragma unroll
      for (int nf = 0; nf < 4; ++nf) {
        half8 wf = *(const half8*)&W[cur][hh][((ks * 4 + g) * 64 + nf * 16 + c) * 8];
        accp[0][nf] = __builtin_amdgcn_mfma_f32_16x16x32_f16(af0, wf, accp[0][nf], 0, 0, 0);
        accp[1][nf] = __builtin_amdgcn_mfma_f32_16x16x32_f16(af1, wf, accp[1][nf], 0, 0, 0);
      }
    }
    DRAIN_BAR();
  }

#pragma unroll
  for (int h2 = 0; h2 < 2; ++h2) {
    const int bh = b * 8 + hp * 2 + h2;
    if (hh == h2) {
      float Lp[4], Lm[4];
#pragma unroll
      for (int nf = 0; nf < 4; ++nf) {
        Lp[nf] = lsc[bh * 128 + nf * 16 + c];
        Lm[nf] = lsc[bh * 128 + 64 + nf * 16 + c];
      }
#pragma unroll
      for (int mf = 0; mf < 2; ++mf) {
        float ss_[4], cm_[4];
#pragma unroll
        for (int j = 0; j < 4; ++j) {
          float s = 0.f;
#pragma unroll
          for (int nf = 0; nf < 4; ++nf) { float q = accp[mf][nf][j]; s = fmaf(q, q, s); }
          s += __shfl_xor(s, 1); s += __shfl_xor(s, 2);
          s += __shfl_xor(s, 4); s += __shfl_xor(s, 8);
          ss_[j] = s * 0.0078125f;
        }
#pragma unroll
        for (int j = 0; j < 4; ++j) {
          float m0 = -1e30f;
#pragma unroll
          for (int nf = 0; nf < 4; ++nf) {
            float v = accp[mf][nf][j];
            m0 = fmaxf(m0, fmaxf(v - ss_[j] + Lp[nf], -v - ss_[j] + Lm[nf]));
            m0 = fmaxf(m0, fmaxf(Lp[nf], Lm[nf]) - 20.723265f);  // eps floor
          }
          m0 = fmaxf(m0, __shfl_xor(m0, 1)); m0 = fmaxf(m0, __shfl_xor(m0, 2));
          m0 = fmaxf(m0, __shfl_xor(m0, 4)); m0 = fmaxf(m0, __shfl_xor(m0, 8));
          cm_[j] = m0;
        }
#pragma unroll
        for (int nf = 0; nf < 4; ++nf) {
          const int m = nf * 16 + c;
#pragma unroll
          for (int j = 0; j < 4; ++j) {
            float v = accp[mf][nf][j];
            _Float16 pp = (_Float16)(__expf(v - ss_[j] + Lp[nf] - cm_[j]) +
                                     1e-9f * __expf(Lp[nf] - cm_[j]));
            _Float16 pm = (_Float16)(__expf(-v - ss_[j] + Lm[nf] - cm_[j]) +
                                     1e-9f * __expf(Lm[nf] - cm_[j]));
            union { unsigned u; _Float16 hhx[2]; } pk;
            pk.hhx[0] = pp; pk.hhx[1] = pm;
            *(unsigned*)&qpT[rq * 32 + mf * 16 + g * 4 + j][2 * m] = pk.u;
          }
        }
      }
    }
    DRAIN_BAR();
    // out-GEMM for head h2 (all waves)
    f32x4 acco[5];
#pragma unroll
    for (int j = 0; j < 5; ++j) acco[j] = (f32x4){0.f, 0.f, 0.f, 0.f};
    const _Float16* kvb = kvnt + (size_t)bh * 10240;
#pragma unroll
    for (int ks = 0; ks < 4; ++ks) {
      half8 a = *(const half8*)&qpT[w * 16 + c][ks * 32 + g * 8];
#pragma unroll
      for (int nf = 0; nf < 5; ++nf) {
        half8 bb = *(const half8*)(kvb + (size_t)(nf * 16 + c) * 128 + ks * 32 + g * 8);
        acco[nf] = __builtin_amdgcn_mfma_f32_16x16x32_f16(a, bb, acco[nf], 0, 0, 0);
      }
    }
    const int tb = t0 + w * 16 + g * 4;
#pragma unroll
    for (int j = 0; j < 4; ++j) {
      float nrm = __shfl(acco[4][j], (lane & 48));
      float invn = 1.0f / nrm;
#pragma unroll
      for (int nf = 0; nf < 4; ++nf) {
        out[((size_t)bh * 4096 + tb + j) * 64 + nf * 16 + c] = acco[nf][j] * invn;
      }
    }
    __builtin_amdgcn_s_barrier();
  }
}

extern "C" void kernel_launch(void* const* d_in, const int* in_sizes, int n_in,
                              void* d_out, int out_size, void* d_ws, size_t ws_size,
                              hipStream_t stream) {
  const float* query = (const float*)d_in[0];
  const float* value = (const float*)d_in[1];
  const float* key   = (const float*)d_in[2];
  const float* wq    = (const float*)d_in[3];
  const float* wv    = (const float*)d_in[4];
  const float* wk    = (const float*)d_in[5];
  const float* omega = (const float*)d_in[6];
  float* out = (float*)d_out;
  char* ws = (char*)d_ws;

  _Float16* wxq  = (_Float16*)(ws);                 // 524288
  _Float16* wxk  = (_Float16*)(ws + 524288);        // 524288
  _Float16* wvt  = (_Float16*)(ws + 1048576);       // 524288
  float* kvpart  = (float*)(ws + 1572864);          // 16*32*10240*4 = 20971520
  _Float16* kvnt = (_Float16*)(ws + 22544384);      // 655360
  float* lsc     = (float*)(ws + 23199744);         // 16384
  float* invbuf  = (float*)(ws + 23216128);         // 16384

  k0_qk<<<256, 256, 0, stream>>>(wq, wk, omega, wxq, wxk);
  k0_v<<<1024, 256, 0, stream>>>(wv, wvt);
  fused_kv<<<256, 512, 0, stream>>>(key, value, wxk, wvt, kvpart);
  k3a_denom<<<32, 128, 0, stream>>>(kvpart, invbuf, lsc);
  k3b_reduce<<<dim3(32, 10), 256, 0, stream>>>(kvpart, invbuf, kvnt);
  fused_qo<<<512, 512, 0, stream>>>(query, wxq, kvnt, lsc, out);
}

// Round 9
// 109.981 us; speedup vs baseline: 1.0528x; 1.0528x over previous
//
#include <hip/hip_runtime.h>

typedef _Float16 half8 __attribute__((ext_vector_type(8)));
typedef _Float16 half4_t __attribute__((ext_vector_type(4)));
typedef short short8 __attribute__((ext_vector_type(8)));
typedef unsigned short u16x4 __attribute__((ext_vector_type(4)));
typedef float f32x4 __attribute__((ext_vector_type(4)));

#define NH 8

__device__ __forceinline__ unsigned short f2bf(float x) {
  union { float f; unsigned u; } v; v.f = x;
  unsigned r = v.u + 0x7FFFu + ((v.u >> 16) & 1u);
  return (unsigned short)(r >> 16);
}

#define DRAIN_BAR()                                  \
  asm volatile("s_waitcnt lgkmcnt(0)" ::: "memory"); \
  __builtin_amdgcn_s_barrier();                      \
  __builtin_amdgcn_sched_barrier(0)

// ---------------- K0a: q/k weights -> fragment-major [h][kc][k8][o][8] fp16 ----
__global__ __launch_bounds__(256) void k0_qk(
    const float* __restrict__ wq, const float* __restrict__ wk,
    const float* __restrict__ omega,
    _Float16* __restrict__ wxq, _Float16* __restrict__ wxk) {
  const int bid = blockIdx.x;
  const int arr = bid >> 7;
  const int h = (bid >> 4) & 7;
  const int ft = (bid >> 1) & 7;
  const int os = bid & 1;
  const int f = threadIdx.x & 63;
  const int w = threadIdx.x >> 6;
  const float* wsrc = (arr ? wk : wq) + ((size_t)h * 512 + ft * 64 + f) * 64;
  float wreg[64];
#pragma unroll
  for (int i = 0; i < 16; ++i) {
    float4 v = *(const float4*)(wsrc + i * 4);
    wreg[i * 4] = v.x; wreg[i * 4 + 1] = v.y; wreg[i * 4 + 2] = v.z; wreg[i * 4 + 3] = v.w;
  }
  _Float16* outp = arr ? wxk : wxq;
  const int k8 = f >> 3, e = f & 7;
#pragma unroll 1
  for (int oo = 0; oo < 8; ++oo) {
    const int o = w * 16 + os * 8 + oo;
    const float* om = omega + o * 64;
    float s = 0.f;
#pragma unroll
    for (int k = 0; k < 64; ++k) s = fmaf(wreg[k], om[k], s);
    outp[((((size_t)h * 8 + ft) * 8 + k8) * 64 + o) * 8 + e] = (_Float16)s;
  }
}

// ---------------- K0b: v weights -> fragment-major [h][kc][k8][o][8] fp16 ------
__global__ __launch_bounds__(256) void k0_v(
    const float* __restrict__ wv, _Float16* __restrict__ wvt) {
  int idx = blockIdx.x * 256 + threadIdx.x;  // 262144
  int h = idx >> 15, o = (idx >> 9) & 63, f = idx & 511;
  float val = wv[((size_t)h * 512 + f) * 64 + o];
  wvt[((((size_t)h * 8 + (f >> 6)) * 8 + ((f >> 3) & 7)) * 64 + o) * 8 + (f & 7)] = (_Float16)val;
}

// ---------------- fused_kv: 2 heads/block, dbuf staging, per-head kv-GEMM ------
// (unchanged from r8 — measured win)
__global__ __launch_bounds__(512, 1) void fused_kv(
    const float* __restrict__ key, const float* __restrict__ value,
    const _Float16* __restrict__ wxk, const _Float16* __restrict__ wvt,
    float* __restrict__ kvpart) {
  __shared__ __align__(16) _Float16 A[2][128][72];       // 36864 B
  __shared__ __align__(16) _Float16 W[2][2][4096];       // 32768 B
  __shared__ __align__(16) unsigned short kpT[128][136]; // 34816 B
  __shared__ __align__(16) unsigned short vT[64][136];   // 17408 B
  const int bid = blockIdx.x;
  const int hp = bid >> 6;
  const int b = (bid >> 4) & 3;
  const int sc = bid & 15;
  const int s0 = sc * 256;
  const int tid = threadIdx.x;
  const int w = tid >> 6;
  const int lane = tid & 63;
  const int g = lane >> 4, c = lane & 15;
  const int hh = w >> 2;
  const int rq = w & 3;
  const int xr = lane >> 4;
  const int xc = (lane & 15) * 4;

  const _Float16* wkb0 = wxk + (size_t)(hp * 2) * 32768;
  const _Float16* wkb1 = wkb0 + 32768;
  const _Float16* wvb0 = wvt + (size_t)(hp * 2) * 32768;
  const _Float16* wvb1 = wvb0 + 32768;

  short8 bones;
#pragma unroll
  for (int i = 0; i < 8; ++i) bones[i] = (c == 0) ? (short)0x3F80 : (short)0;

  f32x4 acc_kv[2][5];
#pragma unroll
  for (int h2 = 0; h2 < 2; ++h2)
#pragma unroll
    for (int j = 0; j < 5; ++j) acc_kv[h2][j] = (f32x4){0.f, 0.f, 0.f, 0.f};

  u16x4 kps[2][4], kms[2][4], vs_[2][4];

  float4 xv[4];
  half8 wr0, wr1;

#pragma unroll 1
  for (int p = 0; p < 4; ++p) {
    const float* xb = ((p & 1) ? value : key) +
                      (size_t)(b * 4096 + s0 + (p >> 1) * 128 + w * 16 + xr) * 512 + xc;
    const _Float16* wb0 = (p & 1) ? wvb0 : wkb0;
    const _Float16* wb1 = (p & 1) ? wvb1 : wkb1;

#pragma unroll
    for (int i = 0; i < 4; ++i) xv[i] = *(const float4*)(xb + i * 2048);
    wr0 = *(const half8*)(wb0 + tid * 8);
    wr1 = *(const half8*)(wb1 + tid * 8);
#pragma unroll
    for (int i = 0; i < 4; ++i) {
      float vv[4] = {xv[i].x, xv[i].y, xv[i].z, xv[i].w};
      half4_t hv;
#pragma unroll
      for (int j2 = 0; j2 < 4; ++j2) hv[j2] = (_Float16)vv[j2];
      *(half4_t*)&A[0][w * 16 + i * 4 + xr][xc] = hv;
    }
    *(half8*)&W[0][0][tid * 8] = wr0;
    *(half8*)&W[0][1][tid * 8] = wr1;
#pragma unroll
    for (int i = 0; i < 4; ++i) xv[i] = *(const float4*)(xb + 64 + i * 2048);
    wr0 = *(const half8*)(wb0 + 4096 + tid * 8);
    wr1 = *(const half8*)(wb1 + 4096 + tid * 8);
    DRAIN_BAR();

    f32x4 accp[2][4];
#pragma unroll
    for (int mf = 0; mf < 2; ++mf)
#pragma unroll
      for (int j = 0; j < 4; ++j) accp[mf][j] = (f32x4){0.f, 0.f, 0.f, 0.f};

#pragma unroll 1
    for (int kc = 0; kc < 8; ++kc) {
      const int cur = kc & 1;
      if (kc < 7) {
        const int nxt = cur ^ 1;
#pragma unroll
        for (int i = 0; i < 4; ++i) {
          float vv[4] = {xv[i].x, xv[i].y, xv[i].z, xv[i].w};
          half4_t hv;
#pragma unroll
          for (int j2 = 0; j2 < 4; ++j2) hv[j2] = (_Float16)vv[j2];
          *(half4_t*)&A[nxt][w * 16 + i * 4 + xr][xc] = hv;
        }
        *(half8*)&W[nxt][0][tid * 8] = wr0;
        *(half8*)&W[nxt][1][tid * 8] = wr1;
        if (kc < 6) {
#pragma unroll
          for (int i = 0; i < 4; ++i)
            xv[i] = *(const float4*)(xb + (kc + 2) * 64 + i * 2048);
          wr0 = *(const half8*)(wb0 + (kc + 2) * 4096 + tid * 8);
          wr1 = *(const half8*)(wb1 + (kc + 2) * 4096 + tid * 8);
        }
      }
#pragma unroll
      for (int ks = 0; ks < 2; ++ks) {
        half8 af0 = *(const half8*)&A[cur][rq * 32 + c][ks * 32 + g * 8];
        half8 af1 = *(const half8*)&A[cur][rq * 32 + 16 + c][ks * 32 + g * 8];
#pragma unroll
        for (int nf = 0; nf < 4; ++nf) {
          half8 wf = *(const half8*)&W[cur][hh][((ks * 4 + g) * 64 + nf * 16 + c) * 8];
          accp[0][nf] = __builtin_amdgcn_mfma_f32_16x16x32_f16(af0, wf, accp[0][nf], 0, 0, 0);
          accp[1][nf] = __builtin_amdgcn_mfma_f32_16x16x32_f16(af1, wf, accp[1][nf], 0, 0, 0);
        }
      }
      DRAIN_BAR();
    }

    if ((p & 1) == 0) {
#pragma unroll
      for (int mf = 0; mf < 2; ++mf) {
        float ss_[4];
#pragma unroll
        for (int j = 0; j < 4; ++j) {
          float s = 0.f;
#pragma unroll
          for (int nf = 0; nf < 4; ++nf) { float q = accp[mf][nf][j]; s = fmaf(q, q, s); }
          s += __shfl_xor(s, 1); s += __shfl_xor(s, 2);
          s += __shfl_xor(s, 4); s += __shfl_xor(s, 8);
          ss_[j] = s * 0.0078125f;
        }
#pragma unroll
        for (int nf = 0; nf < 4; ++nf) {
          u16x4 kp_p, kp_m;
#pragma unroll
          for (int j = 0; j < 4; ++j) {
            float v = accp[mf][nf][j];
            kp_p[j] = f2bf(__expf(v - ss_[j]) + 1e-9f);
            kp_m[j] = f2bf(__expf(-v - ss_[j]) + 1e-9f);
          }
          kps[mf][nf] = kp_p;
          kms[mf][nf] = kp_m;
        }
      }
    } else {
#pragma unroll
      for (int mf = 0; mf < 2; ++mf)
#pragma unroll
        for (int nf = 0; nf < 4; ++nf) {
          u16x4 vv;
#pragma unroll
          for (int j = 0; j < 4; ++j) vv[j] = f2bf(accp[mf][nf][j]);
          vs_[mf][nf] = vv;
        }
#pragma unroll
      for (int h2 = 0; h2 < 2; ++h2) {
        if (hh == h2) {
#pragma unroll
          for (int mf = 0; mf < 2; ++mf)
#pragma unroll
            for (int nf = 0; nf < 4; ++nf) {
              const int m = nf * 16 + c;
              const int sl = rq * 32 + mf * 16 + g * 4;
              *(u16x4*)&kpT[m][sl] = kps[mf][nf];
              *(u16x4*)&kpT[64 + m][sl] = kms[mf][nf];
              *(u16x4*)&vT[m][sl] = vs_[mf][nf];
            }
        }
        DRAIN_BAR();
#pragma unroll
        for (int ks = 0; ks < 4; ++ks) {
          short8 a = *(const short8*)&kpT[w * 16 + c][ks * 32 + g * 8];
#pragma unroll
          for (int nf = 0; nf < 4; ++nf) {
            short8 bb = *(const short8*)&vT[nf * 16 + c][ks * 32 + g * 8];
            acc_kv[h2][nf] = __builtin_amdgcn_mfma_f32_16x16x32_bf16(a, bb, acc_kv[h2][nf], 0, 0, 0);
          }
          acc_kv[h2][4] = __builtin_amdgcn_mfma_f32_16x16x32_bf16(a, bones, acc_kv[h2][4], 0, 0, 0);
        }
        __builtin_amdgcn_s_barrier();
      }
    }
  }

#pragma unroll
  for (int h2 = 0; h2 < 2; ++h2) {
    float* pbase = kvpart + ((size_t)sc * 32 + b * 8 + hp * 2 + h2) * 10240;
#pragma unroll
    for (int nf = 0; nf < 5; ++nf)
#pragma unroll
      for (int j = 0; j < 4; ++j)
        pbase[(w * 16 + g * 4 + j) * 80 + nf * 16 + c] = acc_kv[h2][nf][j];
  }
}

// ---------------- k3a: denominator sums -> inv + lsc (tiny) ----------------
__global__ __launch_bounds__(128) void k3a_denom(
    const float* __restrict__ kvpart, float* __restrict__ invbuf,
    float* __restrict__ lsc) {
  const int bh = blockIdx.x;
  const int m = threadIdx.x;
  const float* base = kvpart + (size_t)bh * 10240 + m * 80 + 64;
  float s = 0.f;
#pragma unroll
  for (int kk = 0; kk < 16; ++kk) s += base[(size_t)kk * 327680];
  invbuf[bh * 128 + m] = 1.0f / s;
  lsc[bh * 128 + m] = __logf(s);
}

// ---------------- k3b: coalesced elementwise reduce + normalize ----------------
__global__ __launch_bounds__(256) void k3b_reduce(
    const float* __restrict__ kvpart, const float* __restrict__ invbuf,
    _Float16* __restrict__ kvnt) {
  const int bh = blockIdx.x;
  const int e0 = blockIdx.y * 1024 + threadIdx.x * 4;
  const int m = e0 / 80;
  const int d0 = e0 - m * 80;
  const float* base = kvpart + (size_t)bh * 10240 + e0;
  f32x4 s = (f32x4){0.f, 0.f, 0.f, 0.f};
#pragma unroll
  for (int kk = 0; kk < 16; ++kk) {
    f32x4 v = *(const f32x4*)(base + (size_t)kk * 327680);
    s += v;
  }
  const float inv = invbuf[bh * 128 + m];
  const int mst = ((m & 63) << 1) | (m >> 6);
  _Float16* outb = kvnt + (size_t)bh * 10240 + mst;
#pragma unroll
  for (int j = 0; j < 4; ++j) {
    const int d = d0 + j;
    float val;
    if (d < 64) val = s[j] * inv;
    else if (d == 64) val = 1.0f;
    else val = 0.f;
    outb[d * 128] = (_Float16)val;
  }
}

// ---------------- fused_qo: 4-wave blocks, 64 t-rows, 4 blocks/CU --------------
// grid 2048 = h(8, top) x rt(256); block 256 = 4 waves x 16 t-rows
__global__ __launch_bounds__(256, 4) void fused_qo(
    const float* __restrict__ query, const _Float16* __restrict__ wxq,
    const _Float16* __restrict__ kvnt, const float* __restrict__ lsc,
    float* __restrict__ out) {
  __shared__ __align__(16) _Float16 A[64][72];     // 9216 B
  __shared__ __align__(16) _Float16 W[4096];       // 8192 B
  __shared__ __align__(16) _Float16 qpT[64][136];  // 17408 B
  const int bid = blockIdx.x;
  const int h = bid >> 8;
  const int rt = bid & 255;
  const int R0 = rt * 64;
  const int b = R0 >> 12;
  const int t0 = R0 & 4095;
  const int bh = b * NH + h;
  const int tid = threadIdx.x;
  const int w = tid >> 6;
  const int lane = tid & 63;
  const int g = lane >> 4, c = lane & 15;
  const int srow = tid >> 2;          // 64 rows
  const int scol = (tid & 3) * 16;    // fp32 col base (16 floats/thread)

  const float* xb = query + (size_t)(R0 + srow) * 512 + scol;
  const _Float16* wb = wxq + (size_t)h * 32768;

  float4 xv[4];
  half8 wr0, wr1;
#pragma unroll
  for (int i = 0; i < 4; ++i) xv[i] = *(const float4*)(xb + i * 4);
  wr0 = *(const half8*)(wb + tid * 8);
  wr1 = *(const half8*)(wb + 2048 + tid * 8);

  f32x4 accp[4];
#pragma unroll
  for (int j = 0; j < 4; ++j) accp[j] = (f32x4){0.f, 0.f, 0.f, 0.f};

#pragma unroll 1
  for (int kc = 0; kc < 8; ++kc) {
    DRAIN_BAR();  // all waves done reading A/W of kc-1
#pragma unroll
    for (int i = 0; i < 4; ++i) {
      float vv[4] = {xv[i].x, xv[i].y, xv[i].z, xv[i].w};
      half4_t hv;
#pragma unroll
      for (int j2 = 0; j2 < 4; ++j2) hv[j2] = (_Float16)vv[j2];
      *(half4_t*)&A[srow][scol + i * 4] = hv;
    }
    *(half8*)&W[tid * 8] = wr0;
    *(half8*)&W[2048 + tid * 8] = wr1;
    if (kc < 7) {
#pragma unroll
      for (int i = 0; i < 4; ++i)
        xv[i] = *(const float4*)(xb + (kc + 1) * 64 + i * 4);
      wr0 = *(const half8*)(wb + (size_t)(kc + 1) * 4096 + tid * 8);
      wr1 = *(const half8*)(wb + (size_t)(kc + 1) * 4096 + 2048 + tid * 8);
    }
    DRAIN_BAR();  // A/W of kc ready
#pragma unroll
    for (int ks = 0; ks < 2; ++ks) {
      half8 a = *(const half8*)&A[w * 16 + c][ks * 32 + g * 8];
#pragma unroll
      for (int nf = 0; nf < 4; ++nf) {
        half8 wf = *(const half8*)&W[((ks * 4 + g) * 64 + nf * 16 + c) * 8];
        accp[nf] = __builtin_amdgcn_mfma_f32_16x16x32_f16(a, wf, accp[nf], 0, 0, 0);
      }
    }
  }

  // phi epilogue -> qpT (fp16, {pp,pm} interleaved along feature)
  float Lp[4], Lm[4];
#pragma unroll
  for (int nf = 0; nf < 4; ++nf) {
    Lp[nf] = lsc[bh * 128 + nf * 16 + c];
    Lm[nf] = lsc[bh * 128 + 64 + nf * 16 + c];
  }
  float ss_[4], cm_[4];
#pragma unroll
  for (int j = 0; j < 4; ++j) {
    float s = 0.f;
#pragma unroll
    for (int nf = 0; nf < 4; ++nf) { float q = accp[nf][j]; s = fmaf(q, q, s); }
    s += __shfl_xor(s, 1); s += __shfl_xor(s, 2);
    s += __shfl_xor(s, 4); s += __shfl_xor(s, 8);
    ss_[j] = s * 0.0078125f;
  }
#pragma unroll
  for (int j = 0; j < 4; ++j) {
    float m0 = -1e30f;
#pragma unroll
    for (int nf = 0; nf < 4; ++nf) {
      float v = accp[nf][j];
      m0 = fmaxf(m0, fmaxf(v - ss_[j] + Lp[nf], -v - ss_[j] + Lm[nf]));
      m0 = fmaxf(m0, fmaxf(Lp[nf], Lm[nf]) - 20.723265f);  // eps floor
    }
    m0 = fmaxf(m0, __shfl_xor(m0, 1)); m0 = fmaxf(m0, __shfl_xor(m0, 2));
    m0 = fmaxf(m0, __shfl_xor(m0, 4)); m0 = fmaxf(m0, __shfl_xor(m0, 8));
    cm_[j] = m0;
  }
#pragma unroll
  for (int nf = 0; nf < 4; ++nf) {
    const int m = nf * 16 + c;
#pragma unroll
    for (int j = 0; j < 4; ++j) {
      float v = accp[nf][j];
      _Float16 pp = (_Float16)(__expf(v - ss_[j] + Lp[nf] - cm_[j]) +
                               1e-9f * __expf(Lp[nf] - cm_[j]));
      _Float16 pm = (_Float16)(__expf(-v - ss_[j] + Lm[nf] - cm_[j]) +
                               1e-9f * __expf(Lm[nf] - cm_[j]));
      union { unsigned u; _Float16 hh[2]; } pk;
      pk.hh[0] = pp; pk.hh[1] = pm;
      *(unsigned*)&qpT[w * 16 + g * 4 + j][2 * m] = pk.u;
    }
  }
  DRAIN_BAR();

  // out-GEMM
  f32x4 acco[5];
#pragma unroll
  for (int j = 0; j < 5; ++j) acco[j] = (f32x4){0.f, 0.f, 0.f, 0.f};
  const _Float16* kvb = kvnt + (size_t)bh * 10240;
#pragma unroll
  for (int ks = 0; ks < 4; ++ks) {
    half8 a = *(const half8*)&qpT[w * 16 + c][ks * 32 + g * 8];
#pragma unroll
    for (int nf = 0; nf < 5; ++nf) {
      half8 bb = *(const half8*)(kvb + (size_t)(nf * 16 + c) * 128 + ks * 32 + g * 8);
      acco[nf] = __builtin_amdgcn_mfma_f32_16x16x32_f16(a, bb, acco[nf], 0, 0, 0);
    }
  }
  const int tb = t0 + w * 16 + g * 4;
#pragma unroll
  for (int j = 0; j < 4; ++j) {
    float nrm = __shfl(acco[4][j], (lane & 48));
    float invn = 1.0f / nrm;
#pragma unroll
    for (int nf = 0; nf < 4; ++nf) {
      out[((size_t)bh * 4096 + tb + j) * 64 + nf * 16 + c] = acco[nf][j] * invn;
    }
  }
}

extern "C" void kernel_launch(void* const* d_in, const int* in_sizes, int n_in,
                              void* d_out, int out_size, void* d_ws, size_t ws_size,
                              hipStream_t stream) {
  const float* query = (const float*)d_in[0];
  const float* value = (const float*)d_in[1];
  const float* key   = (const float*)d_in[2];
  const float* wq    = (const float*)d_in[3];
  const float* wv    = (const float*)d_in[4];
  const float* wk    = (const float*)d_in[5];
  const float* omega = (const float*)d_in[6];
  float* out = (float*)d_out;
  char* ws = (char*)d_ws;

  _Float16* wxq  = (_Float16*)(ws);                 // 524288
  _Float16* wxk  = (_Float16*)(ws + 524288);        // 524288
  _Float16* wvt  = (_Float16*)(ws + 1048576);       // 524288
  float* kvpart  = (float*)(ws + 1572864);          // 20971520
  _Float16* kvnt = (_Float16*)(ws + 22544384);      // 655360
  float* lsc     = (float*)(ws + 23199744);         // 16384
  float* invbuf  = (float*)(ws + 23216128);         // 16384

  k0_qk<<<256, 256, 0, stream>>>(wq, wk, omega, wxq, wxk);
  k0_v<<<1024, 256, 0, stream>>>(wv, wvt);
  fused_kv<<<256, 512, 0, stream>>>(key, value, wxk, wvt, kvpart);
  k3a_denom<<<32, 128, 0, stream>>>(kvpart, invbuf, lsc);
  k3b_reduce<<<dim3(32, 10), 256, 0, stream>>>(kvpart, invbuf, kvnt);
  fused_qo<<<2048, 256, 0, stream>>>(query, wxq, kvnt, lsc, out);
}